// Round 3
// baseline (4587.961 us; speedup 1.0000x reference)
//
#include <hip/hip_runtime.h>

#define N_NODES 50000
#define N_EDGES 600000
#define DIM 128
#define HID 256

// Padded LDS strides (bytes): row-to-row bank step = 4 -> worst 2-way conflict (free).
#define ASTRIDE_E 784   // 48 chunks of 16B used + 1 pad (edge A-tile: 384 bf16)
#define ASTRIDE_N 528   // 32 chunks used + 1 pad (node A-tile: 256 bf16)
#define HSTRIDE   528   // h: 256 bf16 = 512B + pad
#define OSTRIDE   528   // out: 128 f32 = 512B + pad

typedef float  f32x4  __attribute__((ext_vector_type(4), aligned(16), may_alias));
typedef __bf16 bf16x8 __attribute__((ext_vector_type(8), aligned(16), may_alias));

static __device__ inline f32x4 mfma16x16x32(bf16x8 a, bf16x8 b, f32x4 c) {
    return __builtin_amdgcn_mfma_f32_16x16x32_bf16(a, b, c, 0, 0, 0);
}

// load 8 consecutive f32, convert to bf16x8
static __device__ inline bf16x8 load8_f32_to_bf16(const float* __restrict__ p) {
    f32x4 a = *(const f32x4*)p;
    f32x4 b = *(const f32x4*)(p + 4);
    bf16x8 o;
    o[0] = (__bf16)a[0]; o[1] = (__bf16)a[1]; o[2] = (__bf16)a[2]; o[3] = (__bf16)a[3];
    o[4] = (__bf16)b[0]; o[5] = (__bf16)b[1]; o[6] = (__bf16)b[2]; o[7] = (__bf16)b[3];
    return o;
}

// ---------------------------------------------------------------------------
// Weight pre-pack: W [K, Ncols] row-major fp32 -> MFMA B-fragment order, bf16:
// packed[((t*nC + c)*64 + lane)] = bf16x8{ W[t*32 + (lane>>4)*8 + j][c*16 + (lane&15)] }
// ---------------------------------------------------------------------------
__global__ void pack_kernel(const float* __restrict__ W, __bf16* __restrict__ out,
                            int K, int Ncols) {
    int idx = blockIdx.x * 256 + threadIdx.x;
    int total = (K >> 5) * (Ncols >> 4) * 64;
    if (idx >= total) return;
    int lane = idx & 63;
    int tc = idx >> 6;
    int nC = Ncols >> 4;
    int c = tc % nC;
    int t = tc / nC;
    int col = (c << 4) + (lane & 15);
    int k0 = (t << 5) + ((lane >> 4) << 3);
    bf16x8 v;
#pragma unroll
    for (int j = 0; j < 8; ++j) v[j] = (__bf16)W[(k0 + j) * Ncols + col];
    *((bf16x8*)out + idx) = v;
}

// ---------------------------------------------------------------------------
// MLP core: A-tile (32 rows, bf16, stride ASTRIDE) in ldsA.
// h = A@W1+b1 -> LN -> SiLU (bf16 in ldsH) -> out = h@W2+b2 (f32+bias in ldsO).
// ---------------------------------------------------------------------------
template<int ASTRIDE, int K1STEPS>
__device__ inline void mlp_core(const char* ldsA, char* ldsH, char* ldsO,
                                const bf16x8* __restrict__ pW1,
                                const bf16x8* __restrict__ pW2,
                                const float* __restrict__ b1,
                                const float* __restrict__ g1,
                                const float* __restrict__ be1,
                                const float* __restrict__ b2) {
    const int tid = threadIdx.x;
    const int wave = tid >> 6, lane = tid & 63;
    const int mrow = (wave & 1) << 4;    // 0 or 16
    const int l16 = lane & 15;
    const int kgrp = lane >> 4;
    const int arow = mrow + l16;

    // ---- GEMM1: [32,K1] x [K1,256] ----
    {
        const int ncol = (wave >> 1) << 7;  // 0 or 128
        f32x4 acc[8];
#pragma unroll
        for (int f = 0; f < 8; ++f) acc[f] = (f32x4){0.f, 0.f, 0.f, 0.f};
#pragma unroll
        for (int t = 0; t < K1STEPS; ++t) {
            bf16x8 afrag = *(const bf16x8*)(ldsA + arow * ASTRIDE + t * 64 + kgrp * 16);
            const bf16x8* bp = pW1 + ((t * 16 + (ncol >> 4)) << 6) + lane;
#pragma unroll
            for (int f = 0; f < 8; ++f)
                acc[f] = mfma16x16x32(afrag, bp[f << 6], acc[f]);
        }
        // h = acc + b1 -> ldsH (bf16 [32][256])
#pragma unroll
        for (int f = 0; f < 8; ++f) {
            int col = ncol + (f << 4) + l16;
            float bias = b1[col];
#pragma unroll
            for (int r = 0; r < 4; ++r) {
                int row = mrow + kgrp * 4 + r;
                *(__bf16*)(ldsH + row * HSTRIDE + col * 2) = (__bf16)(acc[f][r] + bias);
            }
        }
    }
    __syncthreads();

    // ---- LayerNorm + SiLU in place on ldsH (8 lanes per row, 32 cols each) ----
    {
        int row = tid >> 3;
        int c0 = (tid & 7) << 5;
        float vals[32];
        float sum = 0.f, sq = 0.f;
#pragma unroll
        for (int i = 0; i < 4; ++i) {
            bf16x8 v = *(const bf16x8*)(ldsH + row * HSTRIDE + (c0 + i * 8) * 2);
#pragma unroll
            for (int j = 0; j < 8; ++j) {
                float x = (float)v[j];
                vals[i * 8 + j] = x;
                sum += x; sq += x * x;
            }
        }
        sum += __shfl_xor(sum, 1); sq += __shfl_xor(sq, 1);
        sum += __shfl_xor(sum, 2); sq += __shfl_xor(sq, 2);
        sum += __shfl_xor(sum, 4); sq += __shfl_xor(sq, 4);
        float mu = sum * (1.f / 256.f);
        float var = fmaxf(sq * (1.f / 256.f) - mu * mu, 0.f);
        float rs = rsqrtf(var + 1e-5f);
#pragma unroll
        for (int i = 0; i < 4; ++i) {
            int col = c0 + i * 8;
            f32x4 g0 = *(const f32x4*)(g1 + col);
            f32x4 g4 = *(const f32x4*)(g1 + col + 4);
            f32x4 bb0 = *(const f32x4*)(be1 + col);
            f32x4 bb4 = *(const f32x4*)(be1 + col + 4);
            bf16x8 o;
#pragma unroll
            for (int j = 0; j < 8; ++j) {
                float gj = (j < 4) ? g0[j & 3] : g4[j & 3];
                float bj = (j < 4) ? bb0[j & 3] : bb4[j & 3];
                float x = (vals[i * 8 + j] - mu) * rs * gj + bj;
                x = x / (1.f + __expf(-x));   // SiLU
                o[j] = (__bf16)x;
            }
            *(bf16x8*)(ldsH + row * HSTRIDE + col * 2) = o;
        }
    }
    __syncthreads();

    // ---- GEMM2: [32,256] x [256,128] -> ldsO (f32, +b2) ----
    {
        const int ncol = (wave >> 1) << 6;  // 0 or 64
        f32x4 acc[4];
#pragma unroll
        for (int f = 0; f < 4; ++f) acc[f] = (f32x4){0.f, 0.f, 0.f, 0.f};
#pragma unroll
        for (int t = 0; t < 8; ++t) {
            bf16x8 afrag = *(const bf16x8*)(ldsH + arow * HSTRIDE + t * 64 + kgrp * 16);
            const bf16x8* bp = pW2 + ((t * 8 + (ncol >> 4)) << 6) + lane;
#pragma unroll
            for (int f = 0; f < 4; ++f)
                acc[f] = mfma16x16x32(afrag, bp[f << 6], acc[f]);
        }
#pragma unroll
        for (int f = 0; f < 4; ++f) {
            int col = ncol + (f << 4) + l16;
            float bias = b2[col];
#pragma unroll
            for (int r = 0; r < 4; ++r) {
                int row = mrow + kgrp * 4 + r;
                *(float*)(ldsO + row * OSTRIDE + col * 4) = acc[f][r] + bias;
            }
        }
    }
    __syncthreads();
}

// ---------------------------------------------------------------------------
// Edge kernel: 32 edges/block, 256 threads (4 waves)
// ---------------------------------------------------------------------------
__global__ __launch_bounds__(256) void edge_kernel(
    const float* __restrict__ node, const float* __restrict__ ef,
    const int* __restrict__ eidx,
    const bf16x8* __restrict__ pW1, const bf16x8* __restrict__ pW2,
    const float* __restrict__ b1, const float* __restrict__ g1,
    const float* __restrict__ be1, const float* __restrict__ b2,
    float* __restrict__ agg, float* __restrict__ out_edges) {
    __shared__ __align__(16) char lds[32 * ASTRIDE_E + 32 * HSTRIDE + 32 * OSTRIDE];
    char* ldsA = lds;
    char* ldsH = lds + 32 * ASTRIDE_E;
    char* ldsO = ldsH + 32 * HSTRIDE;
    const int tid = threadIdx.x;
    const int eb = blockIdx.x << 5;

    {   // zero-init LDS (any addressing bug reads 0.0, not junk)
        f32x4 z = (f32x4){0.f, 0.f, 0.f, 0.f};
        const int nchunks = (32 * ASTRIDE_E + 32 * HSTRIDE + 32 * OSTRIDE) / 16;
        for (int i = tid; i < nchunks; i += 256) ((f32x4*)lds)[i] = z;
    }
    __syncthreads();

    {   // stage edge_input = [node[snd] | node[rcv] | ef] : 48 groups of 8 f32 -> bf16
        int row = tid >> 3, l8 = tid & 7;
        int e = eb + row;
        int snd = eidx[e];
        int rcv = eidx[N_EDGES + e];
        snd = (snd < 0) ? 0 : (snd >= N_NODES ? N_NODES - 1 : snd);   // safety clamp
        rcv = (rcv < 0) ? 0 : (rcv >= N_NODES ? N_NODES - 1 : rcv);
        const float* ps = node + (size_t)snd * DIM;
        const float* pr = node + (size_t)rcv * DIM;
        const float* pe = ef + (size_t)e * DIM;
#pragma unroll
        for (int i = 0; i < 6; ++i) {
            int c16 = l8 + (i << 3);
            const float* src = (c16 < 16) ? (ps + (c16 << 3))
                             : (c16 < 32) ? (pr + ((c16 - 16) << 3))
                                          : (pe + ((c16 - 32) << 3));
            *(bf16x8*)(ldsA + row * ASTRIDE_E + (c16 << 4)) = load8_f32_to_bf16(src);
        }
    }
    __syncthreads();

    mlp_core<ASTRIDE_E, 12>(ldsA, ldsH, ldsO, pW1, pW2, b1, g1, be1, b2);

    {   // out = ef + mlp_out (fp32); write fp32 + fp32 atomic scatter-add into agg
        int row = tid >> 3;
        int c0 = (tid & 7) << 4;
        int e = eb + row;
        int rcv = eidx[N_EDGES + e];
        rcv = (rcv < 0) ? 0 : (rcv >= N_NODES ? N_NODES - 1 : rcv);
        float o[16];
#pragma unroll
        for (int i = 0; i < 4; ++i) {
            f32x4 v = *(const f32x4*)(ldsO + row * OSTRIDE + (c0 + i * 4) * 4);
            o[i * 4 + 0] = v[0]; o[i * 4 + 1] = v[1];
            o[i * 4 + 2] = v[2]; o[i * 4 + 3] = v[3];
        }
        const float* pe = ef + (size_t)e * DIM + c0;
#pragma unroll
        for (int i = 0; i < 4; ++i) {
            f32x4 v = *(const f32x4*)(pe + i * 4);
            o[i * 4 + 0] += v[0]; o[i * 4 + 1] += v[1];
            o[i * 4 + 2] += v[2]; o[i * 4 + 3] += v[3];
        }
        float* op = out_edges + (size_t)e * DIM + c0;
#pragma unroll
        for (int i = 0; i < 4; ++i) {
            f32x4 v = {o[i * 4 + 0], o[i * 4 + 1], o[i * 4 + 2], o[i * 4 + 3]};
            *(f32x4*)(op + i * 4) = v;
        }
        float* ap = agg + (size_t)rcv * DIM + c0;
#pragma unroll
        for (int j = 0; j < 16; ++j) unsafeAtomicAdd(ap + j, o[j]);
    }
}

// ---------------------------------------------------------------------------
// Node kernel: 32 nodes/block
// ---------------------------------------------------------------------------
__global__ __launch_bounds__(256) void node_kernel(
    const float* __restrict__ node, const float* __restrict__ agg,
    const bf16x8* __restrict__ pW1, const bf16x8* __restrict__ pW2,
    const float* __restrict__ b1, const float* __restrict__ g1,
    const float* __restrict__ be1, const float* __restrict__ b2,
    float* __restrict__ out_nodes) {
    __shared__ __align__(16) char lds[32 * ASTRIDE_N + 32 * HSTRIDE + 32 * OSTRIDE];
    char* ldsA = lds;
    char* ldsH = lds + 32 * ASTRIDE_N;
    char* ldsO = ldsH + 32 * HSTRIDE;
    const int tid = threadIdx.x;
    const int nb = blockIdx.x << 5;

    {   // zero-init LDS
        f32x4 z = (f32x4){0.f, 0.f, 0.f, 0.f};
        const int nchunks = (32 * ASTRIDE_N + 32 * HSTRIDE + 32 * OSTRIDE) / 16;
        for (int i = tid; i < nchunks; i += 256) ((f32x4*)lds)[i] = z;
    }
    __syncthreads();

    {   // stage node_input = [node[n] | aggregated[n]] : 32 groups of 8 f32 -> bf16
        int row = tid >> 3, l8 = tid & 7;
        int n = nb + row;
        if (n > N_NODES - 1) n = N_NODES - 1;   // clamp (duplicate work, guarded store)
#pragma unroll
        for (int i = 0; i < 4; ++i) {
            int c16 = l8 + (i << 3);
            const float* src = (c16 < 16) ? (node + (size_t)n * DIM + (c16 << 3))
                                          : (agg + (size_t)n * DIM + ((c16 - 16) << 3));
            *(bf16x8*)(ldsA + row * ASTRIDE_N + (c16 << 4)) = load8_f32_to_bf16(src);
        }
    }
    __syncthreads();

    mlp_core<ASTRIDE_N, 8>(ldsA, ldsH, ldsO, pW1, pW2, b1, g1, be1, b2);

    {   // out = node + mlp_out (fp32)
        int row = tid >> 3;
        int c0 = (tid & 7) << 4;
        int n = nb + row;
        if (n < N_NODES) {
            float o[16];
#pragma unroll
            for (int i = 0; i < 4; ++i) {
                f32x4 v = *(const f32x4*)(ldsO + row * OSTRIDE + (c0 + i * 4) * 4);
                o[i * 4 + 0] = v[0]; o[i * 4 + 1] = v[1];
                o[i * 4 + 2] = v[2]; o[i * 4 + 3] = v[3];
            }
            const float* pn = node + (size_t)n * DIM + c0;
#pragma unroll
            for (int i = 0; i < 4; ++i) {
                f32x4 v = *(const f32x4*)(pn + i * 4);
                o[i * 4 + 0] += v[0]; o[i * 4 + 1] += v[1];
                o[i * 4 + 2] += v[2]; o[i * 4 + 3] += v[3];
            }
            float* op = out_nodes + (size_t)n * DIM + c0;
#pragma unroll
            for (int i = 0; i < 4; ++i) {
                f32x4 v = {o[i * 4 + 0], o[i * 4 + 1], o[i * 4 + 2], o[i * 4 + 3]};
                *(f32x4*)(op + i * 4) = v;
            }
        }
    }
}

// ---------------------------------------------------------------------------
extern "C" void kernel_launch(void* const* d_in, const int* in_sizes, int n_in,
                              void* d_out, int out_size, void* d_ws, size_t ws_size,
                              hipStream_t stream) {
    const float* node  = (const float*)d_in[0];
    const float* ef    = (const float*)d_in[1];
    const int*   eidx  = (const int*)d_in[2];
    const float* eW1   = (const float*)d_in[3];
    const float* eb1   = (const float*)d_in[4];
    const float* eg1   = (const float*)d_in[5];
    const float* ebt1  = (const float*)d_in[6];
    const float* eW2   = (const float*)d_in[7];
    const float* eb2   = (const float*)d_in[8];
    const float* nW1   = (const float*)d_in[9];
    const float* nb1   = (const float*)d_in[10];
    const float* ng1   = (const float*)d_in[11];
    const float* nbt1  = (const float*)d_in[12];
    const float* nW2   = (const float*)d_in[13];
    const float* nb2   = (const float*)d_in[14];

    // workspace layout: agg fp32 [50000][128], then packed bf16 weights
    char* ws = (char*)d_ws;
    float* agg = (float*)ws;
    size_t agg_bytes = (size_t)N_NODES * DIM * sizeof(float);       // 25.6 MB
    __bf16* peW1 = (__bf16*)(ws + ((agg_bytes + 255) & ~(size_t)255));
    __bf16* peW2 = peW1 + 384 * 256;
    __bf16* pnW1 = peW2 + 256 * 128;
    __bf16* pnW2 = pnW1 + 256 * 256;

    hipMemsetAsync(agg, 0, agg_bytes, stream);
    pack_kernel<<<48, 256, 0, stream>>>(eW1, peW1, 384, 256);
    pack_kernel<<<16, 256, 0, stream>>>(eW2, peW2, 256, 128);
    pack_kernel<<<32, 256, 0, stream>>>(nW1, pnW1, 256, 256);
    pack_kernel<<<16, 256, 0, stream>>>(nW2, pnW2, 256, 128);

    float* out_nodes = (float*)d_out;
    float* out_edges = out_nodes + (size_t)N_NODES * DIM;

    edge_kernel<<<N_EDGES / 32, 256, 0, stream>>>(
        node, ef, eidx, (const bf16x8*)peW1, (const bf16x8*)peW2,
        eb1, eg1, ebt1, eb2, agg, out_edges);
    node_kernel<<<(N_NODES + 31) / 32, 256, 0, stream>>>(
        node, agg, (const bf16x8*)pnW1, (const bf16x8*)pnW2,
        nb1, ng1, nbt1, nb2, out_nodes);
}

// Round 4
// 880.174 us; speedup vs baseline: 5.2126x; 5.2126x over previous
//
#include <hip/hip_runtime.h>

#define N_NODES 50000
#define N_EDGES 600000
#define DIM 128
#define HID 256

// Padded LDS strides (bytes): row-to-row bank step = 4 -> worst 2-way conflict (free).
#define ASTRIDE_E 784   // 48 chunks of 16B used + 1 pad (edge A-tile: 384 bf16)
#define ASTRIDE_N 528   // 32 chunks used + 1 pad (node A-tile: 256 bf16)
#define HSTRIDE   528   // h: 256 bf16 = 512B + pad
#define OSTRIDE   528   // out: 128 f32 = 512B + pad

typedef float  f32x4  __attribute__((ext_vector_type(4), aligned(16), may_alias));
typedef __bf16 bf16x8 __attribute__((ext_vector_type(8), aligned(16), may_alias));

static __device__ inline f32x4 mfma16x16x32(bf16x8 a, bf16x8 b, f32x4 c) {
    return __builtin_amdgcn_mfma_f32_16x16x32_bf16(a, b, c, 0, 0, 0);
}

// load 8 consecutive f32, convert to bf16x8
static __device__ inline bf16x8 load8_f32_to_bf16(const float* __restrict__ p) {
    f32x4 a = *(const f32x4*)p;
    f32x4 b = *(const f32x4*)(p + 4);
    bf16x8 o;
    o[0] = (__bf16)a[0]; o[1] = (__bf16)a[1]; o[2] = (__bf16)a[2]; o[3] = (__bf16)a[3];
    o[4] = (__bf16)b[0]; o[5] = (__bf16)b[1]; o[6] = (__bf16)b[2]; o[7] = (__bf16)b[3];
    return o;
}

// ---------------------------------------------------------------------------
// Weight pre-pack: W [K, Ncols] row-major fp32 -> MFMA B-fragment order, bf16
// ---------------------------------------------------------------------------
__global__ void pack_kernel(const float* __restrict__ W, __bf16* __restrict__ out,
                            int K, int Ncols) {
    int idx = blockIdx.x * 256 + threadIdx.x;
    int total = (K >> 5) * (Ncols >> 4) * 64;
    if (idx >= total) return;
    int lane = idx & 63;
    int tc = idx >> 6;
    int nC = Ncols >> 4;
    int c = tc % nC;
    int t = tc / nC;
    int col = (c << 4) + (lane & 15);
    int k0 = (t << 5) + ((lane >> 4) << 3);
    bf16x8 v;
#pragma unroll
    for (int j = 0; j < 8; ++j) v[j] = (__bf16)W[(k0 + j) * Ncols + col];
    *((bf16x8*)out + idx) = v;
}

// ---------------------------------------------------------------------------
// CSR build: histogram -> exclusive scan -> scatter edge ids per receiver
// ---------------------------------------------------------------------------
__global__ void hist_kernel(const int* __restrict__ eidx, int* __restrict__ counts) {
    int e = blockIdx.x * 256 + threadIdx.x;
    if (e < N_EDGES) {
        int r = eidx[N_EDGES + e];
        r = (r < 0) ? 0 : (r >= N_NODES ? N_NODES - 1 : r);
        atomicAdd(&counts[r], 1);
    }
}

__global__ __launch_bounds__(1024) void scan_kernel(const int* __restrict__ counts,
                                                    int* __restrict__ offsets,
                                                    int* __restrict__ cursor) {
    __shared__ int part[1024];
    const int t = threadIdx.x;
    const int CH = (N_NODES + 1023) / 1024;   // 49
    const int base = t * CH;
    int s = 0;
#pragma unroll 1
    for (int i = 0; i < CH; ++i) {
        int idx = base + i;
        if (idx < N_NODES) s += counts[idx];
    }
    part[t] = s;
    __syncthreads();
    for (int d = 1; d < 1024; d <<= 1) {
        int x = (t >= d) ? part[t - d] : 0;
        __syncthreads();
        part[t] += x;
        __syncthreads();
    }
    int run = part[t] - s;   // exclusive prefix at chunk start
#pragma unroll 1
    for (int i = 0; i < CH; ++i) {
        int idx = base + i;
        if (idx < N_NODES) {
            offsets[idx] = run;
            cursor[idx]  = run;
            run += counts[idx];
        }
    }
    if (t == 1023) offsets[N_NODES] = run;
}

__global__ void scatter_kernel(const int* __restrict__ eidx,
                               int* __restrict__ cursor, int* __restrict__ eids) {
    int e = blockIdx.x * 256 + threadIdx.x;
    if (e < N_EDGES) {
        int r = eidx[N_EDGES + e];
        r = (r < 0) ? 0 : (r >= N_NODES ? N_NODES - 1 : r);
        int pos = atomicAdd(&cursor[r], 1);
        eids[pos] = e;
    }
}

// ---------------------------------------------------------------------------
// MLP core: A-tile (32 rows, bf16, stride ASTRIDE) in ldsA.
// h = A@W1+b1 -> LN -> SiLU (bf16 in ldsH) -> out = h@W2+b2 (f32+bias in ldsO).
// ldsO may alias ldsA (lifetimes disjoint, barrier-separated).
// ---------------------------------------------------------------------------
template<int ASTRIDE, int K1STEPS>
__device__ inline void mlp_core(char* ldsA, char* ldsH, char* ldsO,
                                const bf16x8* __restrict__ pW1,
                                const bf16x8* __restrict__ pW2,
                                const float* __restrict__ b1,
                                const float* __restrict__ g1,
                                const float* __restrict__ be1,
                                const float* __restrict__ b2) {
    const int tid = threadIdx.x;
    const int wave = tid >> 6, lane = tid & 63;
    const int mrow = (wave & 1) << 4;    // 0 or 16
    const int l16 = lane & 15;
    const int kgrp = lane >> 4;
    const int arow = mrow + l16;

    // ---- GEMM1: [32,K1] x [K1,256] ----
    {
        const int ncol = (wave >> 1) << 7;  // 0 or 128
        f32x4 acc[8];
#pragma unroll
        for (int f = 0; f < 8; ++f) acc[f] = (f32x4){0.f, 0.f, 0.f, 0.f};
#pragma unroll
        for (int t = 0; t < K1STEPS; ++t) {
            bf16x8 afrag = *(const bf16x8*)(ldsA + arow * ASTRIDE + t * 64 + kgrp * 16);
            const bf16x8* bp = pW1 + ((t * 16 + (ncol >> 4)) << 6) + lane;
#pragma unroll
            for (int f = 0; f < 8; ++f)
                acc[f] = mfma16x16x32(afrag, bp[f << 6], acc[f]);
        }
        // h = acc + b1 -> ldsH (bf16 [32][256])
#pragma unroll
        for (int f = 0; f < 8; ++f) {
            int col = ncol + (f << 4) + l16;
            float bias = b1[col];
#pragma unroll
            for (int r = 0; r < 4; ++r) {
                int row = mrow + kgrp * 4 + r;
                *(__bf16*)(ldsH + row * HSTRIDE + col * 2) = (__bf16)(acc[f][r] + bias);
            }
        }
    }
    __syncthreads();

    // ---- LayerNorm + SiLU in place on ldsH (8 lanes per row, 32 cols each) ----
    {
        int row = tid >> 3;
        int c0 = (tid & 7) << 5;
        float vals[32];
        float sum = 0.f, sq = 0.f;
#pragma unroll
        for (int i = 0; i < 4; ++i) {
            bf16x8 v = *(const bf16x8*)(ldsH + row * HSTRIDE + (c0 + i * 8) * 2);
#pragma unroll
            for (int j = 0; j < 8; ++j) {
                float x = (float)v[j];
                vals[i * 8 + j] = x;
                sum += x; sq += x * x;
            }
        }
        sum += __shfl_xor(sum, 1); sq += __shfl_xor(sq, 1);
        sum += __shfl_xor(sum, 2); sq += __shfl_xor(sq, 2);
        sum += __shfl_xor(sum, 4); sq += __shfl_xor(sq, 4);
        float mu = sum * (1.f / 256.f);
        float var = fmaxf(sq * (1.f / 256.f) - mu * mu, 0.f);
        float rs = rsqrtf(var + 1e-5f);
#pragma unroll
        for (int i = 0; i < 4; ++i) {
            int col = c0 + i * 8;
            f32x4 g0 = *(const f32x4*)(g1 + col);
            f32x4 g4 = *(const f32x4*)(g1 + col + 4);
            f32x4 bb0 = *(const f32x4*)(be1 + col);
            f32x4 bb4 = *(const f32x4*)(be1 + col + 4);
            bf16x8 o;
#pragma unroll
            for (int j = 0; j < 8; ++j) {
                float gj = (j < 4) ? g0[j & 3] : g4[j & 3];
                float bj = (j < 4) ? bb0[j & 3] : bb4[j & 3];
                float x = (vals[i * 8 + j] - mu) * rs * gj + bj;
                x = x / (1.f + __expf(-x));   // SiLU
                o[j] = (__bf16)x;
            }
            *(bf16x8*)(ldsH + row * HSTRIDE + col * 2) = o;
        }
    }
    __syncthreads();

    // ---- GEMM2: [32,256] x [256,128] -> ldsO (f32, +b2) ----
    {
        const int ncol = (wave >> 1) << 6;  // 0 or 64
        f32x4 acc[4];
#pragma unroll
        for (int f = 0; f < 4; ++f) acc[f] = (f32x4){0.f, 0.f, 0.f, 0.f};
#pragma unroll
        for (int t = 0; t < 8; ++t) {
            bf16x8 afrag = *(const bf16x8*)(ldsH + arow * HSTRIDE + t * 64 + kgrp * 16);
            const bf16x8* bp = pW2 + ((t * 8 + (ncol >> 4)) << 6) + lane;
#pragma unroll
            for (int f = 0; f < 4; ++f)
                acc[f] = mfma16x16x32(afrag, bp[f << 6], acc[f]);
        }
#pragma unroll
        for (int f = 0; f < 4; ++f) {
            int col = ncol + (f << 4) + l16;
            float bias = b2[col];
#pragma unroll
            for (int r = 0; r < 4; ++r) {
                int row = mrow + kgrp * 4 + r;
                *(float*)(ldsO + row * OSTRIDE + col * 4) = acc[f][r] + bias;
            }
        }
    }
    __syncthreads();
}

// ---------------------------------------------------------------------------
// Edge kernel: 32 edges/block, 256 threads (4 waves). No atomics.
// ---------------------------------------------------------------------------
__global__ __launch_bounds__(256) void edge_kernel(
    const float* __restrict__ node, const float* __restrict__ ef,
    const int* __restrict__ eidx,
    const bf16x8* __restrict__ pW1, const bf16x8* __restrict__ pW2,
    const float* __restrict__ b1, const float* __restrict__ g1,
    const float* __restrict__ be1, const float* __restrict__ b2,
    float* __restrict__ out_edges) {
    __shared__ __align__(16) char lds[32 * ASTRIDE_E + 32 * HSTRIDE];
    char* ldsA = lds;                       // A-tile; later aliased as O (f32)
    char* ldsH = lds + 32 * ASTRIDE_E;
    const int tid = threadIdx.x;
    const int eb = blockIdx.x << 5;

    {   // stage edge_input = [node[snd] | node[rcv] | ef] : 48 groups of 8 f32 -> bf16
        int row = tid >> 3, l8 = tid & 7;
        int e = eb + row;
        int snd = eidx[e];
        int rcv = eidx[N_EDGES + e];
        snd = (snd < 0) ? 0 : (snd >= N_NODES ? N_NODES - 1 : snd);
        rcv = (rcv < 0) ? 0 : (rcv >= N_NODES ? N_NODES - 1 : rcv);
        const float* ps = node + (size_t)snd * DIM;
        const float* pr = node + (size_t)rcv * DIM;
        const float* pe = ef + (size_t)e * DIM;
#pragma unroll
        for (int i = 0; i < 6; ++i) {
            int c16 = l8 + (i << 3);
            const float* src = (c16 < 16) ? (ps + (c16 << 3))
                             : (c16 < 32) ? (pr + ((c16 - 16) << 3))
                                          : (pe + ((c16 - 32) << 3));
            *(bf16x8*)(ldsA + row * ASTRIDE_E + (c16 << 4)) = load8_f32_to_bf16(src);
        }
    }
    __syncthreads();

    mlp_core<ASTRIDE_E, 12>(ldsA, ldsH, /*ldsO=*/ldsA, pW1, pW2, b1, g1, be1, b2);

    {   // out = ef + mlp_out (fp32), streaming write
        int row = tid >> 3;
        int c0 = (tid & 7) << 4;
        int e = eb + row;
        float o[16];
#pragma unroll
        for (int i = 0; i < 4; ++i) {
            f32x4 v = *(const f32x4*)(ldsA + row * OSTRIDE + (c0 + i * 4) * 4);
            o[i * 4 + 0] = v[0]; o[i * 4 + 1] = v[1];
            o[i * 4 + 2] = v[2]; o[i * 4 + 3] = v[3];
        }
        const float* pe = ef + (size_t)e * DIM + c0;
#pragma unroll
        for (int i = 0; i < 4; ++i) {
            f32x4 v = *(const f32x4*)(pe + i * 4);
            o[i * 4 + 0] += v[0]; o[i * 4 + 1] += v[1];
            o[i * 4 + 2] += v[2]; o[i * 4 + 3] += v[3];
        }
        float* op = out_edges + (size_t)e * DIM + c0;
#pragma unroll
        for (int i = 0; i < 4; ++i) {
            f32x4 v = {o[i * 4 + 0], o[i * 4 + 1], o[i * 4 + 2], o[i * 4 + 3]};
            *(f32x4*)(op + i * 4) = v;
        }
    }
}

// ---------------------------------------------------------------------------
// Node kernel: 32 nodes/block; aggregates incident edges via CSR gather.
// aggregated[n] = sum_{e: rcv(e)=n} out_edges[e]  (== new edge features)
// ---------------------------------------------------------------------------
__global__ __launch_bounds__(256) void node_kernel(
    const float* __restrict__ node, const float* __restrict__ out_edges,
    const int* __restrict__ offsets, const int* __restrict__ eids,
    const bf16x8* __restrict__ pW1, const bf16x8* __restrict__ pW2,
    const float* __restrict__ b1, const float* __restrict__ g1,
    const float* __restrict__ be1, const float* __restrict__ b2,
    float* __restrict__ out_nodes) {
    __shared__ __align__(16) char lds[32 * ASTRIDE_N + 32 * HSTRIDE];
    char* ldsA = lds;                       // A-tile; later aliased as O (f32)
    char* ldsH = lds + 32 * ASTRIDE_N;
    const int tid = threadIdx.x;
    const int nb = blockIdx.x << 5;

    {   // stage node_input = [node[n] | csr-gathered aggregate] -> bf16
        int row = tid >> 3, l8 = tid & 7;
        int n = nb + row;
        int nc = (n > N_NODES - 1) ? N_NODES - 1 : n;
        // first 128 cols: node features (chunks l8, l8+8)
#pragma unroll
        for (int i = 0; i < 2; ++i) {
            int c16 = l8 + (i << 3);
            *(bf16x8*)(ldsA + row * ASTRIDE_N + (c16 << 4)) =
                load8_f32_to_bf16(node + (size_t)nc * DIM + (c16 << 3));
        }
        // last 128 cols: aggregate; lane owns 16 contiguous cols [l8*16, l8*16+16)
        float a[16];
#pragma unroll
        for (int j = 0; j < 16; ++j) a[j] = 0.f;
        int st = offsets[nc], en = offsets[nc + 1];
#pragma unroll 1
        for (int i = st; i < en; ++i) {
            int e = eids[i];
            const float* er = out_edges + (size_t)e * DIM + (l8 << 4);
#pragma unroll
            for (int k = 0; k < 4; ++k) {
                f32x4 v = *(const f32x4*)(er + (k << 2));
                a[k * 4 + 0] += v[0]; a[k * 4 + 1] += v[1];
                a[k * 4 + 2] += v[2]; a[k * 4 + 3] += v[3];
            }
        }
        bf16x8 o0, o1;
#pragma unroll
        for (int j = 0; j < 8; ++j) { o0[j] = (__bf16)a[j]; o1[j] = (__bf16)a[8 + j]; }
        int cbase = 16 + (l8 << 1);
        *(bf16x8*)(ldsA + row * ASTRIDE_N + (cbase << 4)) = o0;
        *(bf16x8*)(ldsA + row * ASTRIDE_N + ((cbase + 1) << 4)) = o1;
    }
    __syncthreads();

    mlp_core<ASTRIDE_N, 8>(ldsA, ldsH, /*ldsO=*/ldsA, pW1, pW2, b1, g1, be1, b2);

    {   // out = node + mlp_out (fp32)
        int row = tid >> 3;
        int c0 = (tid & 7) << 4;
        int n = nb + row;
        if (n < N_NODES) {
            float o[16];
#pragma unroll
            for (int i = 0; i < 4; ++i) {
                f32x4 v = *(const f32x4*)(ldsA + row * OSTRIDE + (c0 + i * 4) * 4);
                o[i * 4 + 0] = v[0]; o[i * 4 + 1] = v[1];
                o[i * 4 + 2] = v[2]; o[i * 4 + 3] = v[3];
            }
            const float* pn = node + (size_t)n * DIM + c0;
#pragma unroll
            for (int i = 0; i < 4; ++i) {
                f32x4 v = *(const f32x4*)(pn + i * 4);
                o[i * 4 + 0] += v[0]; o[i * 4 + 1] += v[1];
                o[i * 4 + 2] += v[2]; o[i * 4 + 3] += v[3];
            }
            float* op = out_nodes + (size_t)n * DIM + c0;
#pragma unroll
            for (int i = 0; i < 4; ++i) {
                f32x4 v = {o[i * 4 + 0], o[i * 4 + 1], o[i * 4 + 2], o[i * 4 + 3]};
                *(f32x4*)(op + i * 4) = v;
            }
        }
    }
}

// ---------------------------------------------------------------------------
extern "C" void kernel_launch(void* const* d_in, const int* in_sizes, int n_in,
                              void* d_out, int out_size, void* d_ws, size_t ws_size,
                              hipStream_t stream) {
    const float* node  = (const float*)d_in[0];
    const float* ef    = (const float*)d_in[1];
    const int*   eidx  = (const int*)d_in[2];
    const float* eW1   = (const float*)d_in[3];
    const float* eb1   = (const float*)d_in[4];
    const float* eg1   = (const float*)d_in[5];
    const float* ebt1  = (const float*)d_in[6];
    const float* eW2   = (const float*)d_in[7];
    const float* eb2   = (const float*)d_in[8];
    const float* nW1   = (const float*)d_in[9];
    const float* nb1   = (const float*)d_in[10];
    const float* ng1   = (const float*)d_in[11];
    const float* nbt1  = (const float*)d_in[12];
    const float* nW2   = (const float*)d_in[13];
    const float* nb2   = (const float*)d_in[14];

    // workspace: CSR arrays + packed bf16 weights
    char* ws = (char*)d_ws;
    int* counts  = (int*)ws;                    // 50000 (padded 50016)
    int* offsets = counts + 50016;              // 50001 (padded 50016)
    int* cursor  = offsets + 50016;             // 50000 (padded 50016)
    int* eids    = cursor + 50016;              // 600000
    char* wbase = (char*)(eids + 600064);
    __bf16* peW1 = (__bf16*)(((uintptr_t)wbase + 255) & ~(uintptr_t)255);
    __bf16* peW2 = peW1 + 384 * 256;
    __bf16* pnW1 = peW2 + 256 * 128;
    __bf16* pnW2 = pnW1 + 256 * 256;

    hipMemsetAsync(counts, 0, 50000 * sizeof(int), stream);
    pack_kernel<<<48, 256, 0, stream>>>(eW1, peW1, 384, 256);
    pack_kernel<<<16, 256, 0, stream>>>(eW2, peW2, 256, 128);
    pack_kernel<<<32, 256, 0, stream>>>(nW1, pnW1, 256, 256);
    pack_kernel<<<16, 256, 0, stream>>>(nW2, pnW2, 256, 128);

    hist_kernel<<<(N_EDGES + 255) / 256, 256, 0, stream>>>(eidx, counts);
    scan_kernel<<<1, 1024, 0, stream>>>(counts, offsets, cursor);
    scatter_kernel<<<(N_EDGES + 255) / 256, 256, 0, stream>>>(eidx, cursor, eids);

    float* out_nodes = (float*)d_out;
    float* out_edges = out_nodes + (size_t)N_NODES * DIM;

    edge_kernel<<<N_EDGES / 32, 256, 0, stream>>>(
        node, ef, eidx, (const bf16x8*)peW1, (const bf16x8*)peW2,
        eb1, eg1, ebt1, eb2, out_edges);
    node_kernel<<<(N_NODES + 31) / 32, 256, 0, stream>>>(
        node, out_edges, offsets, eids, (const bf16x8*)pnW1, (const bf16x8*)pnW2,
        nb1, ng1, nbt1, nb2, out_nodes);
}